// Round 4
// baseline (356.851 us; speedup 1.0000x reference)
//
#include <hip/hip_runtime.h>
#include <hip/hip_bf16.h>
#include <math.h>

#define TV_ 1600
#define SCALE_K 2.885390081777927f   // 2*log2(e): folded into fk/pk so tanh uses exp2 directly

typedef __attribute__((ext_vector_type(8))) short bf16x8;
typedef __attribute__((ext_vector_type(4))) float f32x4;

__device__ __forceinline__ float tanh_scaled(float y) {
    y = fminf(44.f, fmaxf(-44.f, y));
    float e = __builtin_amdgcn_exp2f(y);
    float r = __builtin_amdgcn_rcpf(e + 1.f);
    return __builtin_fmaf(e, r, -r);
}

__device__ __forceinline__ ushort f2bf(float f) {
    __hip_bfloat16 h = __float2bfloat16(f);
    return *(ushort*)&h;
}

// ---------------------------------------------------------------------------
// K1: attention per (n,v) block — unchanged from round 3 (127 us, isolated).
// ---------------------------------------------------------------------------
__global__ __launch_bounds__(256, 5) void attn_kernel(
    const float* __restrict__ x, const float* __restrict__ pe,
    const float* __restrict__ dbg, const float* __restrict__ dbb,
    const float* __restrict__ qkv_w, const float* __restrict__ qkv_b,
    const float* __restrict__ attn_w, const float* __restrict__ attn_b,
    float* __restrict__ out, float* __restrict__ se)
{
    __shared__ float sm[8192];
    const int FQ = 0, FK = 1088, FV = 2176, PQ = 3264, PK = 4352, MU = 5440, AO = 5504;

    const int b = blockIdx.x;
    const int l = b >> 3;
    const int n = (b & 7) * 8 + l / 25;
    const int v = l % 25;
    const int tid = threadIdx.x;
    const float rs = rsqrtf(1.f + 1e-5f);
    const float RS2 = 0.70710678118654752f;

    for (int k = 0; k < 16; ++k) {
        int i = tid + k * 256;
        int c = i >> 6, t = i & 63;
        float xv = x[((n * 64 + c) * 64 + t) * 25 + v];
        sm[i] = xv * (dbg[c * 25 + v] * rs) + dbb[c * 25 + v];
        sm[4096 + i] = xv + pe[(c * 64 + t) * 25 + v];
    }
    __syncthreads();

    const int m = tid & 15, g = tid >> 4;
    float accf[3][4] = {{0}}, accp[2][4] = {{0}};
    int rf[3], wrf[3];
    const int rp0 = 2 * g, rp1 = 2 * g + 1;
    #pragma unroll
    for (int k = 0; k < 3; ++k) { int r = 3 * g + k; rf[k] = r; wrf[k] = (r < 32) ? r : r + 16; }

    for (int c0 = 0; c0 < 64; c0 += 4) {
        float wfl[12], wpl[8];
        *(float4*)&wfl[0] = *(const float4*)&qkv_w[wrf[0] * 64 + c0];
        *(float4*)&wfl[4] = *(const float4*)&qkv_w[wrf[1] * 64 + c0];
        *(float4*)&wfl[8] = *(const float4*)&qkv_w[wrf[2] * 64 + c0];
        *(float4*)&wpl[0] = *(const float4*)&qkv_w[rp0 * 64 + c0];
        *(float4*)&wpl[4] = *(const float4*)&qkv_w[rp1 * 64 + c0];
        #pragma unroll
        for (int cc = 0; cc < 4; ++cc) {
            float4 xf = *(const float4*)&sm[(c0 + cc) * 64 + 4 * m];
            float4 yp = *(const float4*)&sm[4096 + (c0 + cc) * 64 + 4 * m];
            #pragma unroll
            for (int k = 0; k < 3; ++k) {
                float w = wfl[k * 4 + cc];
                accf[k][0] += w * xf.x; accf[k][1] += w * xf.y;
                accf[k][2] += w * xf.z; accf[k][3] += w * xf.w;
            }
            #pragma unroll
            for (int k = 0; k < 2; ++k) {
                float w = wpl[k * 4 + cc];
                accp[k][0] += w * yp.x; accp[k][1] += w * yp.y;
                accp[k][2] += w * yp.z; accp[k][3] += w * yp.w;
            }
        }
    }
    float bf[3] = {qkv_b[wrf[0]], qkv_b[wrf[1]], qkv_b[wrf[2]]};
    float bp[2] = {qkv_b[rp0], qkv_b[rp1]};
    __syncthreads();

    #pragma unroll
    for (int k = 0; k < 3; ++k) {
        int r = rf[k];
        int base = (r < 16) ? (FQ + r * 68) : (r < 32) ? (FK + (r - 16) * 68) : (FV + (r - 32) * 68);
        float sc = (r < 16) ? RS2 : (r < 32) ? SCALE_K : 1.f;
        float4 val = make_float4((accf[k][0] + bf[k]) * sc, (accf[k][1] + bf[k]) * sc,
                                 (accf[k][2] + bf[k]) * sc, (accf[k][3] + bf[k]) * sc);
        *(float4*)&sm[base + 4 * m] = val;
    }
    #pragma unroll
    for (int k = 0; k < 2; ++k) {
        int r = (k == 0) ? rp0 : rp1;
        int base = (r < 16) ? (PQ + r * 68) : (PK + (r - 16) * 68);
        float sc = (r < 16) ? RS2 : SCALE_K;
        float4 val = make_float4((accp[k][0] + bp[k]) * sc, (accp[k][1] + bp[k]) * sc,
                                 (accp[k][2] + bp[k]) * sc, (accp[k][3] + bp[k]) * sc);
        *(float4*)&sm[base + 4 * m] = val;
    }
    __syncthreads();

    if (tid < 64) {
        int ch = tid & 15, q = tid >> 4;
        float s = 0.f;
        #pragma unroll
        for (int t = 0; t < 16; ++t) s += sm[FQ + ch * 68 + q * 16 + t];
        sm[MU + q * 16 + ch] = s;
    }
    __syncthreads();
    if (tid < 16) {
        float mval = (sm[MU + tid] + sm[MU + 16 + tid] + sm[MU + 32 + tid] + sm[MU + 48 + tid]) * (1.f / 64.f);
        sm[MU + tid] = mval;
    }
    __syncthreads();

    const int g3 = tid & 7, m3 = tid >> 3;
    for (int h = 0; h < 8; ++h) {
        const int row0 = 2 * h * 68, row1 = row0 + 68;
        float mux = sm[MU + 2 * h], muy = sm[MU + 2 * h + 1];
        float fk0[8], fk1[8], pk0[8], pk1[8], fv0[8], fv1[8], un[8];
        #pragma unroll
        for (int jt = 0; jt < 8; ++jt) {
            int t = 8 * g3 + jt;
            fk0[jt] = sm[FK + row0 + t]; fk1[jt] = sm[FK + row1 + t];
            pk0[jt] = sm[PK + row0 + t]; pk1[jt] = sm[PK + row1 + t];
            fv0[jt] = sm[FV + row0 + t]; fv1[jt] = sm[FV + row1 + t];
            un[jt] = mux * fk0[jt] + muy * fk1[jt];
        }
        float ao[2][2] = {{0.f, 0.f}, {0.f, 0.f}};
        #pragma unroll
        for (int js = 0; js < 2; ++js) {
            int s = 2 * m3 + js;
            float fq0 = sm[FQ + row0 + s] - mux, fq1 = sm[FQ + row1 + s] - muy;
            float pq0 = sm[PQ + row0 + s], pq1 = sm[PQ + row1 + s];
            #pragma unroll
            for (int jt = 0; jt < 8; ++jt) {
                float lp = pq0 * pk0[jt] + pq1 * pk1[jt];
                float a1 = fq0 * fk0[jt] + fq1 * fk1[jt] + lp;
                float a2 = un[jt] + lp;
                float w = tanh_scaled(a1) + tanh_scaled(a2);
                ao[js][0] += w * fv0[jt];
                ao[js][1] += w * fv1[jt];
            }
        }
        #pragma unroll
        for (int off = 1; off <= 4; off <<= 1) {
            ao[0][0] += __shfl_xor(ao[0][0], off);
            ao[0][1] += __shfl_xor(ao[0][1], off);
            ao[1][0] += __shfl_xor(ao[1][0], off);
            ao[1][1] += __shfl_xor(ao[1][1], off);
        }
        if (g3 == 0) {
            sm[AO + (2 * m3) * 20 + 2 * h]         = ao[0][0];
            sm[AO + (2 * m3) * 20 + 2 * h + 1]     = ao[0][1];
            sm[AO + (2 * m3 + 1) * 20 + 2 * h]     = ao[1][0];
            sm[AO + (2 * m3 + 1) * 20 + 2 * h + 1] = ao[1][1];
        }
    }
    __syncthreads();

    const int t = tid & 63, oq = tid >> 6;
    float aorow[16];
    #pragma unroll
    for (int i = 0; i < 4; ++i)
        *(float4*)&aorow[i * 4] = *(const float4*)&sm[AO + t * 20 + i * 4];
    #pragma unroll
    for (int j = 0; j < 4; ++j) {
        int o = oq * 4 + j;
        float acc = attn_b[o];
        #pragma unroll
        for (int ch = 0; ch < 16; ++ch) acc += attn_w[o * 16 + ch] * aorow[ch];
        float res = acc + x[((n * 64 + 48 + o) * 64 + t) * 25 + v];
        out[((n * 64 + 48 + o) * 64 + t) * 25 + v] = res;
        float ssum = res;
        #pragma unroll
        for (int off = 32; off >= 1; off >>= 1) ssum += __shfl_down(ssum, off, 64);
        if ((tid & 63) == 0) atomicAdd(&se[n * 64 + 48 + o], ssum);
    }
}

// ---------------------------------------------------------------------------
// wb_prep: W[oc][k=kt*64+ci] = bf16( tcn_w[oc][ci][kt] * bn_gain[oc] )
// ---------------------------------------------------------------------------
__global__ __launch_bounds__(256) void wb_prep_kernel(
    const float* __restrict__ tcn_w, const float* __restrict__ tg, ushort* __restrict__ wb)
{
    int idx = blockIdx.x * 256 + threadIdx.x;
    if (idx >= 48 * 576) return;
    int oc = idx / 576, kk = idx - oc * 576;
    int kt = kk >> 6, ci = kk & 63;
    float a = tg[oc] * rsqrtf(1.f + 1e-5f);
    wb[idx] = f2bf(tcn_w[(oc * 64 + ci) * 9 + kt] * a);
}

// ---------------------------------------------------------------------------
// K2: tcn as bf16 MFMA implicit GEMM.
// Block = (n, pos-tile of 400 = 16t x 25v). Grid 256, 512 threads (8 waves).
// LDS: xsl[pos'=600][ci, stride 72] bf16 (86.4 KB) — t-halo of +-4 staged once.
// K = 576 = 18 tiles of 32, k = kt*64+ci. A = wb (global, L2-hot).
// Frag recipe (m89/m92/m120): a[j]=A[lane&15][q*8+j], b[j]=B[lane&15][q*8+j],
// D[q*4+reg][lane&15]; rowD = A's M (oc), colD = B's N (pos).
// ---------------------------------------------------------------------------
__global__ __launch_bounds__(512, 1) void tcn_mfma_kernel(
    const float* __restrict__ x, const ushort* __restrict__ wb,
    const float* __restrict__ tcn_b, const float* __restrict__ tg,
    const float* __restrict__ tb, float* __restrict__ out, float* __restrict__ se)
{
    __shared__ ushort xsl[600 * 72];
    const int b = blockIdx.x;
    const int n = b >> 2, tile = b & 3;
    const int t0 = tile * 16;
    const int tid = threadIdx.x;

    // stage x[n][ci][t0-4 .. t0+19][v] -> xsl[(lt*25+v)][ci], bf16, zero OOB
    for (int idx = tid; idx < 64 * 600; idx += 512) {
        int ci = idx / 600, r = idx - ci * 600;       // r = lt*25+v, lt in 0..23
        int tg_ = t0 - 4 + r / 25;
        int v = r % 25;
        float val = (tg_ >= 0 && tg_ < 64) ? x[((n * 64 + ci) * 64 + tg_) * 25 + v] : 0.f;
        xsl[r * 72 + ci] = f2bf(val);
    }
    __syncthreads();

    const int lane = tid & 63, wave = tid >> 6;
    const int m16 = lane & 15, q = lane >> 4;

    // wave handles N-tiles nt = wave, wave+8, wave+16 (wave 0 also 24)
    int myN[4]; int nT = 0;
    for (int nt = wave; nt < 25; nt += 8) myN[nT++] = nt;

    f32x4 acc[4][3];
    for (int i = 0; i < 4; ++i)
        for (int mt = 0; mt < 3; ++mt)
            acc[i][mt] = (f32x4){0.f, 0.f, 0.f, 0.f};

    for (int ktile = 0; ktile < 18; ++ktile) {
        const int kt = ktile >> 1;
        const int cib = (ktile & 1) * 32 + q * 8;
        bf16x8 afr[3];
        #pragma unroll
        for (int mt = 0; mt < 3; ++mt)
            afr[mt] = *(const bf16x8*)&wb[(mt * 16 + m16) * 576 + ktile * 32 + q * 8];
        for (int i = 0; i < nT; ++i) {
            int p = myN[i] * 16 + m16;
            bf16x8 bfr = *(const bf16x8*)&xsl[(p + kt * 25) * 72 + cib];
            #pragma unroll
            for (int mt = 0; mt < 3; ++mt)
                acc[i][mt] = __builtin_amdgcn_mfma_f32_16x16x32_bf16(afr[mt], bfr, acc[i][mt], 0, 0, 0);
        }
    }

    // epilogue: bias' + residual + out + se
    const float rsbn = rsqrtf(1.f + 1e-5f);
    float bias3[3][4], ssum[3][4];
    #pragma unroll
    for (int mt = 0; mt < 3; ++mt)
        #pragma unroll
        for (int r = 0; r < 4; ++r) {
            int oc = mt * 16 + q * 4 + r;
            bias3[mt][r] = tcn_b[oc] * (tg[oc] * rsbn) + tb[oc];
            ssum[mt][r] = 0.f;
        }
    for (int i = 0; i < nT; ++i) {
        int posg = tile * 400 + myN[i] * 16 + m16;
        #pragma unroll
        for (int mt = 0; mt < 3; ++mt) {
            #pragma unroll
            for (int r = 0; r < 4; ++r) {
                int oc = mt * 16 + q * 4 + r;
                float val = acc[i][mt][r] + bias3[mt][r] + x[(n * 64 + oc) * TV_ + posg];
                out[(n * 64 + oc) * TV_ + posg] = val;
                ssum[mt][r] += val;
            }
        }
    }
    #pragma unroll
    for (int mt = 0; mt < 3; ++mt) {
        #pragma unroll
        for (int r = 0; r < 4; ++r) {
            float s = ssum[mt][r];
            #pragma unroll
            for (int off = 1; off <= 8; off <<= 1) s += __shfl_xor(s, off);
            if (m16 == 0) {
                int oc = mt * 16 + q * 4 + r;
                atomicAdd(&se[n * 64 + oc], s);
            }
        }
    }
}

// ---------------------------------------------------------------------------
// K3: SE gate MLP per n
// ---------------------------------------------------------------------------
__global__ __launch_bounds__(64) void gate_kernel(
    const float* __restrict__ se,
    const float* __restrict__ fc1w, const float* __restrict__ fc1b,
    const float* __restrict__ fc2w, const float* __restrict__ fc2b,
    float* __restrict__ gate)
{
    const int n = blockIdx.x;
    const int tid = threadIdx.x;
    __shared__ float seL[64], hid[32];
    seL[tid] = se[n * 64 + tid] * (1.f / (float)TV_);
    __syncthreads();
    if (tid < 32) {
        float a = fc1b[tid];
        #pragma unroll
        for (int c = 0; c < 64; ++c) a += fc1w[tid * 64 + c] * seL[c];
        hid[tid] = fmaxf(a, 0.f);
    }
    __syncthreads();
    float gacc = fc2b[tid];
    #pragma unroll
    for (int j = 0; j < 32; ++j) gacc += fc2w[tid * 32 + j] * hid[j];
    gate[n * 64 + tid] = 1.f / (1.f + __expf(-gacc));
}

// ---------------------------------------------------------------------------
// K4: out = relu((result*(1+gate)) * bn_s + bn_b)
// ---------------------------------------------------------------------------
__global__ __launch_bounds__(256) void final_kernel(
    float* __restrict__ out, const float* __restrict__ gate,
    const float* __restrict__ bng, const float* __restrict__ bnb)
{
    const float rs = rsqrtf(1.f + 1e-5f);
    int idx4 = blockIdx.x * 256 + threadIdx.x;
    if (idx4 >= 1638400) return;
    int nc = idx4 / 400;
    int c = nc & 63;
    float4 val = ((const float4*)out)[idx4];
    float mm = (1.f + gate[nc]) * (bng[c] * rs);
    float bb = bnb[c];
    val.x = fmaxf(val.x * mm + bb, 0.f);
    val.y = fmaxf(val.y * mm + bb, 0.f);
    val.z = fmaxf(val.z * mm + bb, 0.f);
    val.w = fmaxf(val.w * mm + bb, 0.f);
    ((float4*)out)[idx4] = val;
}

extern "C" void kernel_launch(void* const* d_in, const int* in_sizes, int n_in,
                              void* d_out, int out_size, void* d_ws, size_t ws_size,
                              hipStream_t stream) {
    const float* x     = (const float*)d_in[0];
    const float* pe    = (const float*)d_in[1];
    const float* dbg   = (const float*)d_in[2];
    const float* dbb   = (const float*)d_in[3];
    const float* qkvw  = (const float*)d_in[4];
    const float* qkvb  = (const float*)d_in[5];
    const float* attnw = (const float*)d_in[6];
    const float* attnb = (const float*)d_in[7];
    const float* tcnw  = (const float*)d_in[8];
    const float* tcnb  = (const float*)d_in[9];
    const float* tcng  = (const float*)d_in[10];
    const float* tcnbb = (const float*)d_in[11];
    const float* fc1w  = (const float*)d_in[12];
    const float* fc1b  = (const float*)d_in[13];
    const float* fc2w  = (const float*)d_in[14];
    const float* fc2b  = (const float*)d_in[15];
    const float* bng   = (const float*)d_in[16];
    const float* bnb   = (const float*)d_in[17];

    float* out  = (float*)d_out;
    float* se   = (float*)d_ws;             // 4096 floats
    float* gate = se + 4096;                // 4096 floats
    ushort* wb  = (ushort*)(gate + 4096);   // 48*576 bf16

    hipMemsetAsync(se, 0, 4096 * sizeof(float), stream);
    wb_prep_kernel<<<dim3(108), dim3(256), 0, stream>>>(tcnw, tcng, wb);
    attn_kernel<<<dim3(1600), dim3(256), 0, stream>>>(x, pe, dbg, dbb, qkvw, qkvb, attnw, attnb, out, se);
    tcn_mfma_kernel<<<dim3(256), dim3(512), 0, stream>>>(x, wb, tcnb, tcng, tcnbb, out, se);
    gate_kernel<<<dim3(64), dim3(64), 0, stream>>>(se, fc1w, fc1b, fc2w, fc2b, gate);
    final_kernel<<<dim3(6400), dim3(256), 0, stream>>>(out, gate, bng, bnb);
}

// Round 5
// 278.088 us; speedup vs baseline: 1.2832x; 1.2832x over previous
//
#include <hip/hip_runtime.h>
#include <hip/hip_bf16.h>
#include <math.h>

#define TV_ 1600
#define SCALE_K 2.885390081777927f   // 2*log2(e): folded into fk/pk so tanh uses exp2 directly

typedef __attribute__((ext_vector_type(8))) short bf16x8;
typedef __attribute__((ext_vector_type(4))) float f32x4;

__device__ __forceinline__ float tanh_scaled(float y) {
    y = fminf(44.f, fmaxf(-44.f, y));
    float e = __builtin_amdgcn_exp2f(y);
    float r = __builtin_amdgcn_rcpf(e + 1.f);
    return __builtin_fmaf(e, r, -r);
}

__device__ __forceinline__ ushort f2bf(float f) {
    __hip_bfloat16 h = __float2bfloat16(f);
    return *(ushort*)&h;
}

// ---------------------------------------------------------------------------
// K1: attention per (n,v) block — unchanged (steady ~129 us, isolated).
// ---------------------------------------------------------------------------
__global__ __launch_bounds__(256, 5) void attn_kernel(
    const float* __restrict__ x, const float* __restrict__ pe,
    const float* __restrict__ dbg, const float* __restrict__ dbb,
    const float* __restrict__ qkv_w, const float* __restrict__ qkv_b,
    const float* __restrict__ attn_w, const float* __restrict__ attn_b,
    float* __restrict__ out, float* __restrict__ se)
{
    __shared__ float sm[8192];
    const int FQ = 0, FK = 1088, FV = 2176, PQ = 3264, PK = 4352, MU = 5440, AO = 5504;

    const int b = blockIdx.x;
    const int l = b >> 3;
    const int n = (b & 7) * 8 + l / 25;
    const int v = l % 25;
    const int tid = threadIdx.x;
    const float rs = rsqrtf(1.f + 1e-5f);
    const float RS2 = 0.70710678118654752f;

    for (int k = 0; k < 16; ++k) {
        int i = tid + k * 256;
        int c = i >> 6, t = i & 63;
        float xv = x[((n * 64 + c) * 64 + t) * 25 + v];
        sm[i] = xv * (dbg[c * 25 + v] * rs) + dbb[c * 25 + v];
        sm[4096 + i] = xv + pe[(c * 64 + t) * 25 + v];
    }
    __syncthreads();

    const int m = tid & 15, g = tid >> 4;
    float accf[3][4] = {{0}}, accp[2][4] = {{0}};
    int rf[3], wrf[3];
    const int rp0 = 2 * g, rp1 = 2 * g + 1;
    #pragma unroll
    for (int k = 0; k < 3; ++k) { int r = 3 * g + k; rf[k] = r; wrf[k] = (r < 32) ? r : r + 16; }

    for (int c0 = 0; c0 < 64; c0 += 4) {
        float wfl[12], wpl[8];
        *(float4*)&wfl[0] = *(const float4*)&qkv_w[wrf[0] * 64 + c0];
        *(float4*)&wfl[4] = *(const float4*)&qkv_w[wrf[1] * 64 + c0];
        *(float4*)&wfl[8] = *(const float4*)&qkv_w[wrf[2] * 64 + c0];
        *(float4*)&wpl[0] = *(const float4*)&qkv_w[rp0 * 64 + c0];
        *(float4*)&wpl[4] = *(const float4*)&qkv_w[rp1 * 64 + c0];
        #pragma unroll
        for (int cc = 0; cc < 4; ++cc) {
            float4 xf = *(const float4*)&sm[(c0 + cc) * 64 + 4 * m];
            float4 yp = *(const float4*)&sm[4096 + (c0 + cc) * 64 + 4 * m];
            #pragma unroll
            for (int k = 0; k < 3; ++k) {
                float w = wfl[k * 4 + cc];
                accf[k][0] += w * xf.x; accf[k][1] += w * xf.y;
                accf[k][2] += w * xf.z; accf[k][3] += w * xf.w;
            }
            #pragma unroll
            for (int k = 0; k < 2; ++k) {
                float w = wpl[k * 4 + cc];
                accp[k][0] += w * yp.x; accp[k][1] += w * yp.y;
                accp[k][2] += w * yp.z; accp[k][3] += w * yp.w;
            }
        }
    }
    float bf[3] = {qkv_b[wrf[0]], qkv_b[wrf[1]], qkv_b[wrf[2]]};
    float bp[2] = {qkv_b[rp0], qkv_b[rp1]};
    __syncthreads();

    #pragma unroll
    for (int k = 0; k < 3; ++k) {
        int r = rf[k];
        int base = (r < 16) ? (FQ + r * 68) : (r < 32) ? (FK + (r - 16) * 68) : (FV + (r - 32) * 68);
        float sc = (r < 16) ? RS2 : (r < 32) ? SCALE_K : 1.f;
        float4 val = make_float4((accf[k][0] + bf[k]) * sc, (accf[k][1] + bf[k]) * sc,
                                 (accf[k][2] + bf[k]) * sc, (accf[k][3] + bf[k]) * sc);
        *(float4*)&sm[base + 4 * m] = val;
    }
    #pragma unroll
    for (int k = 0; k < 2; ++k) {
        int r = (k == 0) ? rp0 : rp1;
        int base = (r < 16) ? (PQ + r * 68) : (PK + (r - 16) * 68);
        float sc = (r < 16) ? RS2 : SCALE_K;
        float4 val = make_float4((accp[k][0] + bp[k]) * sc, (accp[k][1] + bp[k]) * sc,
                                 (accp[k][2] + bp[k]) * sc, (accp[k][3] + bp[k]) * sc);
        *(float4*)&sm[base + 4 * m] = val;
    }
    __syncthreads();

    if (tid < 64) {
        int ch = tid & 15, q = tid >> 4;
        float s = 0.f;
        #pragma unroll
        for (int t = 0; t < 16; ++t) s += sm[FQ + ch * 68 + q * 16 + t];
        sm[MU + q * 16 + ch] = s;
    }
    __syncthreads();
    if (tid < 16) {
        float mval = (sm[MU + tid] + sm[MU + 16 + tid] + sm[MU + 32 + tid] + sm[MU + 48 + tid]) * (1.f / 64.f);
        sm[MU + tid] = mval;
    }
    __syncthreads();

    const int g3 = tid & 7, m3 = tid >> 3;
    for (int h = 0; h < 8; ++h) {
        const int row0 = 2 * h * 68, row1 = row0 + 68;
        float mux = sm[MU + 2 * h], muy = sm[MU + 2 * h + 1];
        float fk0[8], fk1[8], pk0[8], pk1[8], fv0[8], fv1[8], un[8];
        #pragma unroll
        for (int jt = 0; jt < 8; ++jt) {
            int t = 8 * g3 + jt;
            fk0[jt] = sm[FK + row0 + t]; fk1[jt] = sm[FK + row1 + t];
            pk0[jt] = sm[PK + row0 + t]; pk1[jt] = sm[PK + row1 + t];
            fv0[jt] = sm[FV + row0 + t]; fv1[jt] = sm[FV + row1 + t];
            un[jt] = mux * fk0[jt] + muy * fk1[jt];
        }
        float ao[2][2] = {{0.f, 0.f}, {0.f, 0.f}};
        #pragma unroll
        for (int js = 0; js < 2; ++js) {
            int s = 2 * m3 + js;
            float fq0 = sm[FQ + row0 + s] - mux, fq1 = sm[FQ + row1 + s] - muy;
            float pq0 = sm[PQ + row0 + s], pq1 = sm[PQ + row1 + s];
            #pragma unroll
            for (int jt = 0; jt < 8; ++jt) {
                float lp = pq0 * pk0[jt] + pq1 * pk1[jt];
                float a1 = fq0 * fk0[jt] + fq1 * fk1[jt] + lp;
                float a2 = un[jt] + lp;
                float w = tanh_scaled(a1) + tanh_scaled(a2);
                ao[js][0] += w * fv0[jt];
                ao[js][1] += w * fv1[jt];
            }
        }
        #pragma unroll
        for (int off = 1; off <= 4; off <<= 1) {
            ao[0][0] += __shfl_xor(ao[0][0], off);
            ao[0][1] += __shfl_xor(ao[0][1], off);
            ao[1][0] += __shfl_xor(ao[1][0], off);
            ao[1][1] += __shfl_xor(ao[1][1], off);
        }
        if (g3 == 0) {
            sm[AO + (2 * m3) * 20 + 2 * h]         = ao[0][0];
            sm[AO + (2 * m3) * 20 + 2 * h + 1]     = ao[0][1];
            sm[AO + (2 * m3 + 1) * 20 + 2 * h]     = ao[1][0];
            sm[AO + (2 * m3 + 1) * 20 + 2 * h + 1] = ao[1][1];
        }
    }
    __syncthreads();

    const int t = tid & 63, oq = tid >> 6;
    float aorow[16];
    #pragma unroll
    for (int i = 0; i < 4; ++i)
        *(float4*)&aorow[i * 4] = *(const float4*)&sm[AO + t * 20 + i * 4];
    #pragma unroll
    for (int j = 0; j < 4; ++j) {
        int o = oq * 4 + j;
        float acc = attn_b[o];
        #pragma unroll
        for (int ch = 0; ch < 16; ++ch) acc += attn_w[o * 16 + ch] * aorow[ch];
        float res = acc + x[((n * 64 + 48 + o) * 64 + t) * 25 + v];
        out[((n * 64 + 48 + o) * 64 + t) * 25 + v] = res;
        float ssum = res;
        #pragma unroll
        for (int off = 32; off >= 1; off >>= 1) ssum += __shfl_down(ssum, off, 64);
        if ((tid & 63) == 0) atomicAdd(&se[n * 64 + 48 + o], ssum);
    }
}

// ---------------------------------------------------------------------------
// wb_prep: W[oc][k=kt*64+ci] = bf16( tcn_w[oc][ci][kt] * bn_gain[oc] )
// ---------------------------------------------------------------------------
__global__ __launch_bounds__(256) void wb_prep_kernel(
    const float* __restrict__ tcn_w, const float* __restrict__ tg, ushort* __restrict__ wb)
{
    int idx = blockIdx.x * 256 + threadIdx.x;
    if (idx >= 48 * 576) return;
    int oc = idx / 576, kk = idx - oc * 576;
    int kt = kk >> 6, ci = kk & 63;
    float a = tg[oc] * rsqrtf(1.f + 1e-5f);
    wb[idx] = f2bf(tcn_w[(oc * 64 + ci) * 9 + kt] * a);
}

// ---------------------------------------------------------------------------
// K2: tcn as bf16 MFMA implicit GEMM — STATIC N-tile assignment this round.
// Block = (n, pos-tile of 400). Grid 256, 512 threads (8 waves).
// Wave w owns N-tiles {3w, 3w+1, 3w+2}; tile 24 handled by wave 0 (acc24).
// All accumulator indexing is compile-time -> stays in VGPRs (round-4 bug:
// runtime-bounded loop forced acc[] to scratch -> 182 MB spill traffic).
// ---------------------------------------------------------------------------
__global__ __launch_bounds__(512, 1) void tcn_mfma_kernel(
    const float* __restrict__ x, const ushort* __restrict__ wb,
    const float* __restrict__ tcn_b, const float* __restrict__ tg,
    const float* __restrict__ tb, float* __restrict__ out, float* __restrict__ se)
{
    __shared__ ushort xsl[600 * 72];
    const int b = blockIdx.x;
    const int n = b >> 2, tile = b & 3;
    const int t0 = tile * 16;
    const int tid = threadIdx.x;

    // stage x[n][ci][t0-4 .. t0+19][v] -> xsl[(lt*25+v)][ci], bf16, zero OOB
    for (int idx = tid; idx < 64 * 600; idx += 512) {
        int ci = idx / 600, r = idx - ci * 600;
        int tg_ = t0 - 4 + r / 25;
        int v = r % 25;
        float val = (tg_ >= 0 && tg_ < 64) ? x[((n * 64 + ci) * 64 + tg_) * 25 + v] : 0.f;
        xsl[r * 72 + ci] = f2bf(val);
    }
    __syncthreads();

    const int lane = tid & 63, wave = tid >> 6;
    const int m16 = lane & 15, q = lane >> 4;
    const int nt0 = wave * 3;

    f32x4 acc[3][3];
    f32x4 acc24[3];
    #pragma unroll
    for (int i = 0; i < 3; ++i)
        #pragma unroll
        for (int mt = 0; mt < 3; ++mt)
            acc[i][mt] = (f32x4){0.f, 0.f, 0.f, 0.f};
    #pragma unroll
    for (int mt = 0; mt < 3; ++mt) acc24[mt] = (f32x4){0.f, 0.f, 0.f, 0.f};

    for (int ktile = 0; ktile < 18; ++ktile) {
        const int kt = ktile >> 1;
        const int cib = (ktile & 1) * 32 + q * 8;
        bf16x8 afr[3];
        #pragma unroll
        for (int mt = 0; mt < 3; ++mt)
            afr[mt] = *(const bf16x8*)&wb[(mt * 16 + m16) * 576 + ktile * 32 + q * 8];
        #pragma unroll
        for (int i = 0; i < 3; ++i) {
            int p = (nt0 + i) * 16 + m16;
            bf16x8 bfr = *(const bf16x8*)&xsl[(p + kt * 25) * 72 + cib];
            #pragma unroll
            for (int mt = 0; mt < 3; ++mt)
                acc[i][mt] = __builtin_amdgcn_mfma_f32_16x16x32_bf16(afr[mt], bfr, acc[i][mt], 0, 0, 0);
        }
        if (wave == 0) {
            int p = 24 * 16 + m16;
            bf16x8 bfr = *(const bf16x8*)&xsl[(p + kt * 25) * 72 + cib];
            #pragma unroll
            for (int mt = 0; mt < 3; ++mt)
                acc24[mt] = __builtin_amdgcn_mfma_f32_16x16x32_bf16(afr[mt], bfr, acc24[mt], 0, 0, 0);
        }
    }

    // epilogue: bias' + residual + out + se
    const float rsbn = rsqrtf(1.f + 1e-5f);
    float bias3[3][4], ssum[3][4];
    #pragma unroll
    for (int mt = 0; mt < 3; ++mt)
        #pragma unroll
        for (int r = 0; r < 4; ++r) {
            int oc = mt * 16 + q * 4 + r;
            bias3[mt][r] = tcn_b[oc] * (tg[oc] * rsbn) + tb[oc];
            ssum[mt][r] = 0.f;
        }
    #pragma unroll
    for (int i = 0; i < 3; ++i) {
        int posg = tile * 400 + (nt0 + i) * 16 + m16;
        #pragma unroll
        for (int mt = 0; mt < 3; ++mt) {
            #pragma unroll
            for (int r = 0; r < 4; ++r) {
                int oc = mt * 16 + q * 4 + r;
                float val = acc[i][mt][r] + bias3[mt][r] + x[(n * 64 + oc) * TV_ + posg];
                out[(n * 64 + oc) * TV_ + posg] = val;
                ssum[mt][r] += val;
            }
        }
    }
    if (wave == 0) {
        int posg = tile * 400 + 24 * 16 + m16;
        #pragma unroll
        for (int mt = 0; mt < 3; ++mt) {
            #pragma unroll
            for (int r = 0; r < 4; ++r) {
                int oc = mt * 16 + q * 4 + r;
                float val = acc24[mt][r] + bias3[mt][r] + x[(n * 64 + oc) * TV_ + posg];
                out[(n * 64 + oc) * TV_ + posg] = val;
                ssum[mt][r] += val;
            }
        }
    }
    #pragma unroll
    for (int mt = 0; mt < 3; ++mt) {
        #pragma unroll
        for (int r = 0; r < 4; ++r) {
            float s = ssum[mt][r];
            #pragma unroll
            for (int off = 1; off <= 8; off <<= 1) s += __shfl_xor(s, off);
            if (m16 == 0) {
                int oc = mt * 16 + q * 4 + r;
                atomicAdd(&se[n * 64 + oc], s);
            }
        }
    }
}

// ---------------------------------------------------------------------------
// K3: SE gate MLP per n
// ---------------------------------------------------------------------------
__global__ __launch_bounds__(64) void gate_kernel(
    const float* __restrict__ se,
    const float* __restrict__ fc1w, const float* __restrict__ fc1b,
    const float* __restrict__ fc2w, const float* __restrict__ fc2b,
    float* __restrict__ gate)
{
    const int n = blockIdx.x;
    const int tid = threadIdx.x;
    __shared__ float seL[64], hid[32];
    seL[tid] = se[n * 64 + tid] * (1.f / (float)TV_);
    __syncthreads();
    if (tid < 32) {
        float a = fc1b[tid];
        #pragma unroll
        for (int c = 0; c < 64; ++c) a += fc1w[tid * 64 + c] * seL[c];
        hid[tid] = fmaxf(a, 0.f);
    }
    __syncthreads();
    float gacc = fc2b[tid];
    #pragma unroll
    for (int j = 0; j < 32; ++j) gacc += fc2w[tid * 32 + j] * hid[j];
    gate[n * 64 + tid] = 1.f / (1.f + __expf(-gacc));
}

// ---------------------------------------------------------------------------
// K4: out = relu((result*(1+gate)) * bn_s + bn_b)
// ---------------------------------------------------------------------------
__global__ __launch_bounds__(256) void final_kernel(
    float* __restrict__ out, const float* __restrict__ gate,
    const float* __restrict__ bng, const float* __restrict__ bnb)
{
    const float rs = rsqrtf(1.f + 1e-5f);
    int idx4 = blockIdx.x * 256 + threadIdx.x;
    if (idx4 >= 1638400) return;
    int nc = idx4 / 400;
    int c = nc & 63;
    float4 val = ((const float4*)out)[idx4];
    float mm = (1.f + gate[nc]) * (bng[c] * rs);
    float bb = bnb[c];
    val.x = fmaxf(val.x * mm + bb, 0.f);
    val.y = fmaxf(val.y * mm + bb, 0.f);
    val.z = fmaxf(val.z * mm + bb, 0.f);
    val.w = fmaxf(val.w * mm + bb, 0.f);
    ((float4*)out)[idx4] = val;
}

extern "C" void kernel_launch(void* const* d_in, const int* in_sizes, int n_in,
                              void* d_out, int out_size, void* d_ws, size_t ws_size,
                              hipStream_t stream) {
    const float* x     = (const float*)d_in[0];
    const float* pe    = (const float*)d_in[1];
    const float* dbg   = (const float*)d_in[2];
    const float* dbb   = (const float*)d_in[3];
    const float* qkvw  = (const float*)d_in[4];
    const float* qkvb  = (const float*)d_in[5];
    const float* attnw = (const float*)d_in[6];
    const float* attnb = (const float*)d_in[7];
    const float* tcnw  = (const float*)d_in[8];
    const float* tcnb  = (const float*)d_in[9];
    const float* tcng  = (const float*)d_in[10];
    const float* tcnbb = (const float*)d_in[11];
    const float* fc1w  = (const float*)d_in[12];
    const float* fc1b  = (const float*)d_in[13];
    const float* fc2w  = (const float*)d_in[14];
    const float* fc2b  = (const float*)d_in[15];
    const float* bng   = (const float*)d_in[16];
    const float* bnb   = (const float*)d_in[17];

    float* out  = (float*)d_out;
    float* se   = (float*)d_ws;             // 4096 floats
    float* gate = se + 4096;                // 4096 floats
    ushort* wb  = (ushort*)(gate + 4096);   // 48*576 bf16

    hipMemsetAsync(se, 0, 4096 * sizeof(float), stream);
    wb_prep_kernel<<<dim3(108), dim3(256), 0, stream>>>(tcnw, tcng, wb);
    attn_kernel<<<dim3(1600), dim3(256), 0, stream>>>(x, pe, dbg, dbb, qkvw, qkvb, attnw, attnb, out, se);
    tcn_mfma_kernel<<<dim3(256), dim3(512), 0, stream>>>(x, wb, tcnb, tcng, tcnbb, out, se);
    gate_kernel<<<dim3(64), dim3(64), 0, stream>>>(se, fc1w, fc1b, fc2w, fc2b, gate);
    final_kernel<<<dim3(6400), dim3(256), 0, stream>>>(out, gate, bng, bnb);
}

// Round 6
// 242.740 us; speedup vs baseline: 1.4701x; 1.1456x over previous
//
#include <hip/hip_runtime.h>
#include <hip/hip_bf16.h>
#include <math.h>

#define TV_ 1600
#define SCALE_K 2.885390081777927f   // 2*log2(e): folded into fk/pk rows so tanh uses exp2 directly
#define RS2_ 0.70710678118654752f    // DKH^-0.5 folded into fq/pq rows

typedef __attribute__((ext_vector_type(8))) short bf16x8;
typedef __attribute__((ext_vector_type(4))) float f32x4;

__device__ __forceinline__ float tanh_scaled(float y) {
    y = fminf(44.f, fmaxf(-44.f, y));
    float e = __builtin_amdgcn_exp2f(y);
    float r = __builtin_amdgcn_rcpf(e + 1.f);
    return __builtin_fmaf(e, r, -r);
}

__device__ __forceinline__ ushort f2bf(float f) {
    __hip_bfloat16 h = __float2bfloat16(f);
    return *(ushort*)&h;
}

// ---------------------------------------------------------------------------
// prep: wb (tcn weights, bn-folded bf16), wq (qkv weights, scale-folded bf16),
//       qb (qkv bias, scale-folded fp32)
// wq rows: 0-15 fq(RS2) 16-31 fk(SK) 32-47 fv(1, src rows 48-63) 48-63 pq(RS2)
//          64-79 pk(SK)
// ---------------------------------------------------------------------------
__global__ __launch_bounds__(256) void prep_kernel(
    const float* __restrict__ tcn_w, const float* __restrict__ tg,
    const float* __restrict__ qkv_w, const float* __restrict__ qkv_b,
    ushort* __restrict__ wb, ushort* __restrict__ wq, float* __restrict__ qb)
{
    int idx = blockIdx.x * 256 + threadIdx.x;
    if (idx < 27648) {
        int oc = idx / 576, kk = idx - oc * 576;
        int kt = kk >> 6, ci = kk & 63;
        float a = tg[oc] * rsqrtf(1.f + 1e-5f);
        wb[idx] = f2bf(tcn_w[(oc * 64 + ci) * 9 + kt] * a);
    } else if (idx < 32768) {
        int i2 = idx - 27648;
        int r = i2 >> 6, c = i2 & 63;
        int src; float sc;
        if (r < 16)      { src = r;      sc = RS2_; }
        else if (r < 32) { src = r;      sc = SCALE_K; }
        else if (r < 48) { src = r + 16; sc = 1.f; }
        else if (r < 64) { src = r - 48; sc = RS2_; }
        else             { src = r - 48; sc = SCALE_K; }
        wq[i2] = f2bf(qkv_w[src * 64 + c] * sc);
    } else if (idx < 32848) {
        int r = idx - 32768;
        int src; float sc;
        if (r < 16)      { src = r;      sc = RS2_; }
        else if (r < 32) { src = r;      sc = SCALE_K; }
        else if (r < 48) { src = r + 16; sc = 1.f; }
        else if (r < 64) { src = r - 48; sc = RS2_; }
        else             { src = r - 48; sc = SCALE_K; }
        qb[r] = qkv_b[src] * sc;
    }
}

// ---------------------------------------------------------------------------
// K1: score kernel per (n,v). LDS 39.5 KB -> 4 blocks/CU.
//  phase 1: stage xn=bn(x), yb=x+pe as bf16 [t][ci] (stride 72, 16B-aligned)
//  phase 2: qkv via MFMA (80x64 @ 64x64): wave w owns t-tile w; D -> fp32
//           [row][66] planes + scaled bias
//  phase 3: mu; per-head tanh scores + PV with shfl reduce (unchanged)
//  phase 4: attn_w proj + x residual; COALESCED write to aoc workspace + se
// ---------------------------------------------------------------------------
__global__ __launch_bounds__(256, 4) void score_kernel(
    const float* __restrict__ x, const float* __restrict__ pe,
    const float* __restrict__ dbg, const float* __restrict__ dbb,
    const ushort* __restrict__ wq, const float* __restrict__ qb,
    const float* __restrict__ attn_w, const float* __restrict__ attn_b,
    float* __restrict__ aoc, float* __restrict__ se)
{
    __shared__ float sm[9888];           // [0..4607]: bf16 xn/yb planes (as ushort), later MU/AO
    ushort* smu = (ushort*)sm;           // xn @0, yb @4608 (each 64 t x 72 ci)
    const int QK = 4608;                 // fp32 planes: row r at QK + r*66, r in 0..79
    const int MU = 0, AO = 16;

    const int b = blockIdx.x;
    const int l = b >> 3;
    const int n = (b & 7) * 8 + l / 25;  // same-n blocks share an XCD
    const int v = l % 25;
    const int tid = threadIdx.x;
    const float rs = rsqrtf(1.f + 1e-5f);

    // phase 1: stage bf16 transposed planes
    for (int i = tid; i < 4096; i += 256) {
        int ci = i >> 6, t = i & 63;
        float xv = x[((n * 64 + ci) * 64 + t) * 25 + v];
        float xnv = xv * (dbg[ci * 25 + v] * rs) + dbb[ci * 25 + v];
        float ybv = xv + pe[(ci * 64 + t) * 25 + v];
        smu[t * 72 + ci] = f2bf(xnv);
        smu[4608 + t * 72 + ci] = f2bf(ybv);
    }
    __syncthreads();

    // phase 2: qkv MFMA. wave w -> t-tile w (t = w*16 + m16)
    const int lane = tid & 63, wave = tid >> 6;
    const int m16 = lane & 15, q = lane >> 4;
    {
        f32x4 acc[5];
        #pragma unroll
        for (int mt = 0; mt < 5; ++mt) acc[mt] = (f32x4){0.f, 0.f, 0.f, 0.f};
        #pragma unroll
        for (int kt = 0; kt < 2; ++kt) {
            const int koff = kt * 32 + q * 8;
            bf16x8 bx = *(const bf16x8*)&smu[(wave * 16 + m16) * 72 + koff];
            bf16x8 by = *(const bf16x8*)&smu[4608 + (wave * 16 + m16) * 72 + koff];
            #pragma unroll
            for (int mt = 0; mt < 5; ++mt) {
                bf16x8 a = *(const bf16x8*)&wq[(mt * 16 + m16) * 64 + koff];
                acc[mt] = __builtin_amdgcn_mfma_f32_16x16x32_bf16(a, (mt < 3) ? bx : by, acc[mt], 0, 0, 0);
            }
        }
        __syncthreads();   // xn/yb reads done; QK region writes begin
        #pragma unroll
        for (int mt = 0; mt < 5; ++mt) {
            #pragma unroll
            for (int r = 0; r < 4; ++r) {
                int row = mt * 16 + q * 4 + r;
                sm[QK + row * 66 + wave * 16 + m16] = acc[mt][r] + qb[row];
            }
        }
    }
    __syncthreads();

    // mu over t for the 16 fq channels (rows 0-15)
    if (tid < 64) {
        int ch = tid & 15, qq = tid >> 4;
        float s = 0.f;
        #pragma unroll
        for (int t = 0; t < 16; ++t) s += sm[QK + ch * 66 + qq * 16 + t];
        sm[MU + qq * 16 + ch] = s;   // NOTE: low region reuse; xn/yb dead
    }
    __syncthreads();
    if (tid < 16) {
        float mval = (sm[MU + tid] + sm[MU + 16 + tid] + sm[MU + 32 + tid] + sm[MU + 48 + tid]) * (1.f / 64.f);
        sm[MU + tid] = mval;
    }
    __syncthreads();

    // phase 3: per head; thread tile 2 s x 8 t
    const int g3 = tid & 7, m3 = tid >> 3;
    const int FQb = QK, FKb = QK + 16 * 66, FVb = QK + 32 * 66, PQb = QK + 48 * 66, PKb = QK + 64 * 66;
    for (int h = 0; h < 8; ++h) {
        const int row0 = 2 * h * 66, row1 = row0 + 66;
        float mux = sm[MU + 2 * h], muy = sm[MU + 2 * h + 1];
        float fk0[8], fk1[8], pk0[8], pk1[8], fv0[8], fv1[8], un[8];
        #pragma unroll
        for (int jt = 0; jt < 8; ++jt) {
            int t = 8 * g3 + jt;
            fk0[jt] = sm[FKb + row0 + t]; fk1[jt] = sm[FKb + row1 + t];
            pk0[jt] = sm[PKb + row0 + t]; pk1[jt] = sm[PKb + row1 + t];
            fv0[jt] = sm[FVb + row0 + t]; fv1[jt] = sm[FVb + row1 + t];
            un[jt] = mux * fk0[jt] + muy * fk1[jt];
        }
        float ao[2][2] = {{0.f, 0.f}, {0.f, 0.f}};
        #pragma unroll
        for (int js = 0; js < 2; ++js) {
            int s = 2 * m3 + js;
            float fq0 = sm[FQb + row0 + s] - mux, fq1 = sm[FQb + row1 + s] - muy;
            float pq0 = sm[PQb + row0 + s], pq1 = sm[PQb + row1 + s];
            #pragma unroll
            for (int jt = 0; jt < 8; ++jt) {
                float lp = pq0 * pk0[jt] + pq1 * pk1[jt];
                float a1 = fq0 * fk0[jt] + fq1 * fk1[jt] + lp;
                float a2 = un[jt] + lp;
                float w = tanh_scaled(a1) + tanh_scaled(a2);
                ao[js][0] += w * fv0[jt];
                ao[js][1] += w * fv1[jt];
            }
        }
        #pragma unroll
        for (int off = 1; off <= 4; off <<= 1) {
            ao[0][0] += __shfl_xor(ao[0][0], off);
            ao[0][1] += __shfl_xor(ao[0][1], off);
            ao[1][0] += __shfl_xor(ao[1][0], off);
            ao[1][1] += __shfl_xor(ao[1][1], off);
        }
        if (g3 == 0) {
            sm[AO + (2 * m3) * 20 + 2 * h]         = ao[0][0];
            sm[AO + (2 * m3) * 20 + 2 * h + 1]     = ao[0][1];
            sm[AO + (2 * m3 + 1) * 20 + 2 * h]     = ao[1][0];
            sm[AO + (2 * m3 + 1) * 20 + 2 * h + 1] = ao[1][1];
        }
    }
    __syncthreads();

    // phase 4: attn_w proj + residual; coalesced aoc write + se atomics
    const int t = tid & 63, oq = tid >> 6;
    float aorow[16];
    #pragma unroll
    for (int i = 0; i < 4; ++i)
        *(float4*)&aorow[i * 4] = *(const float4*)&sm[AO + t * 20 + i * 4];
    float* aop = aoc + (n * 25 + v) * 1024;
    #pragma unroll
    for (int j = 0; j < 4; ++j) {
        int o = oq * 4 + j;
        float acc = attn_b[o];
        #pragma unroll
        for (int ch = 0; ch < 16; ++ch) acc += attn_w[o * 16 + ch] * aorow[ch];
        float res = acc + x[((n * 64 + 48 + o) * 64 + t) * 25 + v];
        aop[o * 64 + t] = res;                    // coalesced 256B per wave
        float ssum = res;
        #pragma unroll
        for (int off = 32; off >= 1; off >>= 1) ssum += __shfl_down(ssum, off, 64);
        if ((tid & 63) == 0) atomicAdd(&se[n * 64 + 48 + o], ssum);
    }
}

// ---------------------------------------------------------------------------
// K2: tcn as bf16 MFMA implicit GEMM (unchanged from round 5)
// ---------------------------------------------------------------------------
__global__ __launch_bounds__(512, 1) void tcn_mfma_kernel(
    const float* __restrict__ x, const ushort* __restrict__ wb,
    const float* __restrict__ tcn_b, const float* __restrict__ tg,
    const float* __restrict__ tb, float* __restrict__ out, float* __restrict__ se)
{
    __shared__ ushort xsl[600 * 72];
    const int b = blockIdx.x;
    const int n = b >> 2, tile = b & 3;
    const int t0 = tile * 16;
    const int tid = threadIdx.x;

    for (int idx = tid; idx < 64 * 600; idx += 512) {
        int ci = idx / 600, r = idx - ci * 600;
        int tg_ = t0 - 4 + r / 25;
        int v = r % 25;
        float val = (tg_ >= 0 && tg_ < 64) ? x[((n * 64 + ci) * 64 + tg_) * 25 + v] : 0.f;
        xsl[r * 72 + ci] = f2bf(val);
    }
    __syncthreads();

    const int lane = tid & 63, wave = tid >> 6;
    const int m16 = lane & 15, q = lane >> 4;
    const int nt0 = wave * 3;

    f32x4 acc[3][3];
    f32x4 acc24[3];
    #pragma unroll
    for (int i = 0; i < 3; ++i)
        #pragma unroll
        for (int mt = 0; mt < 3; ++mt)
            acc[i][mt] = (f32x4){0.f, 0.f, 0.f, 0.f};
    #pragma unroll
    for (int mt = 0; mt < 3; ++mt) acc24[mt] = (f32x4){0.f, 0.f, 0.f, 0.f};

    for (int ktile = 0; ktile < 18; ++ktile) {
        const int kt = ktile >> 1;
        const int cib = (ktile & 1) * 32 + q * 8;
        bf16x8 afr[3];
        #pragma unroll
        for (int mt = 0; mt < 3; ++mt)
            afr[mt] = *(const bf16x8*)&wb[(mt * 16 + m16) * 576 + ktile * 32 + q * 8];
        #pragma unroll
        for (int i = 0; i < 3; ++i) {
            int p = (nt0 + i) * 16 + m16;
            bf16x8 bfr = *(const bf16x8*)&xsl[(p + kt * 25) * 72 + cib];
            #pragma unroll
            for (int mt = 0; mt < 3; ++mt)
                acc[i][mt] = __builtin_amdgcn_mfma_f32_16x16x32_bf16(afr[mt], bfr, acc[i][mt], 0, 0, 0);
        }
        if (wave == 0) {
            int p = 24 * 16 + m16;
            bf16x8 bfr = *(const bf16x8*)&xsl[(p + kt * 25) * 72 + cib];
            #pragma unroll
            for (int mt = 0; mt < 3; ++mt)
                acc24[mt] = __builtin_amdgcn_mfma_f32_16x16x32_bf16(afr[mt], bfr, acc24[mt], 0, 0, 0);
        }
    }

    const float rsbn = rsqrtf(1.f + 1e-5f);
    float bias3[3][4], ssum[3][4];
    #pragma unroll
    for (int mt = 0; mt < 3; ++mt)
        #pragma unroll
        for (int r = 0; r < 4; ++r) {
            int oc = mt * 16 + q * 4 + r;
            bias3[mt][r] = tcn_b[oc] * (tg[oc] * rsbn) + tb[oc];
            ssum[mt][r] = 0.f;
        }
    #pragma unroll
    for (int i = 0; i < 3; ++i) {
        int posg = tile * 400 + (nt0 + i) * 16 + m16;
        #pragma unroll
        for (int mt = 0; mt < 3; ++mt) {
            #pragma unroll
            for (int r = 0; r < 4; ++r) {
                int oc = mt * 16 + q * 4 + r;
                float val = acc[i][mt][r] + bias3[mt][r] + x[(n * 64 + oc) * TV_ + posg];
                out[(n * 64 + oc) * TV_ + posg] = val;
                ssum[mt][r] += val;
            }
        }
    }
    if (wave == 0) {
        int posg = tile * 400 + 24 * 16 + m16;
        #pragma unroll
        for (int mt = 0; mt < 3; ++mt) {
            #pragma unroll
            for (int r = 0; r < 4; ++r) {
                int oc = mt * 16 + q * 4 + r;
                float val = acc24[mt][r] + bias3[mt][r] + x[(n * 64 + oc) * TV_ + posg];
                out[(n * 64 + oc) * TV_ + posg] = val;
                ssum[mt][r] += val;
            }
        }
    }
    #pragma unroll
    for (int mt = 0; mt < 3; ++mt) {
        #pragma unroll
        for (int r = 0; r < 4; ++r) {
            float s = ssum[mt][r];
            #pragma unroll
            for (int off = 1; off <= 8; off <<= 1) s += __shfl_xor(s, off);
            if (m16 == 0) {
                int oc = mt * 16 + q * 4 + r;
                atomicAdd(&se[n * 64 + oc], s);
            }
        }
    }
}

// ---------------------------------------------------------------------------
// K3: SE gate MLP per n
// ---------------------------------------------------------------------------
__global__ __launch_bounds__(64) void gate_kernel(
    const float* __restrict__ se,
    const float* __restrict__ fc1w, const float* __restrict__ fc1b,
    const float* __restrict__ fc2w, const float* __restrict__ fc2b,
    float* __restrict__ gate)
{
    const int n = blockIdx.x;
    const int tid = threadIdx.x;
    __shared__ float seL[64], hid[32];
    seL[tid] = se[n * 64 + tid] * (1.f / (float)TV_);
    __syncthreads();
    if (tid < 32) {
        float a = fc1b[tid];
        #pragma unroll
        for (int c = 0; c < 64; ++c) a += fc1w[tid * 64 + c] * seL[c];
        hid[tid] = fmaxf(a, 0.f);
    }
    __syncthreads();
    float gacc = fc2b[tid];
    #pragma unroll
    for (int j = 0; j < 32; ++j) gacc += fc2w[tid * 32 + j] * hid[j];
    gate[n * 64 + tid] = 1.f / (1.f + __expf(-gacc));
}

// ---------------------------------------------------------------------------
// K4: assemble + gate + BN + relu. c<48: read out (tcn result). c>=48: gather
// from aoc (already includes residual).
// ---------------------------------------------------------------------------
__global__ __launch_bounds__(256) void final_kernel(
    float* __restrict__ out, const float* __restrict__ aoc,
    const float* __restrict__ gate,
    const float* __restrict__ bng, const float* __restrict__ bnb)
{
    const float rs = rsqrtf(1.f + 1e-5f);
    int idx4 = blockIdx.x * 256 + threadIdx.x;
    if (idx4 >= 1638400) return;
    int nc = idx4 / 400;
    int c = nc & 63, n = nc >> 6;
    float4 val;
    if (c < 48) {
        val = ((const float4*)out)[idx4];
    } else {
        int rem = idx4 - nc * 400;
        const float* ap = aoc + n * 25600 + (c - 48) * 64;
        #pragma unroll
        for (int e = 0; e < 4; ++e) {
            int pos = rem * 4 + e;
            int t = pos / 25, v = pos - t * 25;
            ((float*)&val)[e] = ap[v * 1024 + t];
        }
    }
    float mm = (1.f + gate[nc]) * (bng[c] * rs);
    float bb = bnb[c];
    val.x = fmaxf(val.x * mm + bb, 0.f);
    val.y = fmaxf(val.y * mm + bb, 0.f);
    val.z = fmaxf(val.z * mm + bb, 0.f);
    val.w = fmaxf(val.w * mm + bb, 0.f);
    ((float4*)out)[idx4] = val;
}

extern "C" void kernel_launch(void* const* d_in, const int* in_sizes, int n_in,
                              void* d_out, int out_size, void* d_ws, size_t ws_size,
                              hipStream_t stream) {
    const float* x     = (const float*)d_in[0];
    const float* pe    = (const float*)d_in[1];
    const float* dbg   = (const float*)d_in[2];
    const float* dbb   = (const float*)d_in[3];
    const float* qkvw  = (const float*)d_in[4];
    const float* qkvb  = (const float*)d_in[5];
    const float* attnw = (const float*)d_in[6];
    const float* attnb = (const float*)d_in[7];
    const float* tcnw  = (const float*)d_in[8];
    const float* tcnb  = (const float*)d_in[9];
    const float* tcng  = (const float*)d_in[10];
    const float* tcnbb = (const float*)d_in[11];
    const float* fc1w  = (const float*)d_in[12];
    const float* fc1b  = (const float*)d_in[13];
    const float* fc2w  = (const float*)d_in[14];
    const float* fc2b  = (const float*)d_in[15];
    const float* bng   = (const float*)d_in[16];
    const float* bnb   = (const float*)d_in[17];

    float* out  = (float*)d_out;
    float* se   = (float*)d_ws;                      // 4096 f
    float* gate = se + 4096;                         // 4096 f
    float* qb   = gate + 4096;                       // 80 f (pad to 96)
    float* aoc  = qb + 96;                           // 1,638,400 f
    ushort* wb  = (ushort*)(aoc + 1638400);          // 27648 u16
    ushort* wq  = wb + 27648;                        // 5120 u16

    hipMemsetAsync(se, 0, 4096 * sizeof(float), stream);
    prep_kernel<<<dim3(129), dim3(256), 0, stream>>>(tcnw, tcng, qkvw, qkvb, wb, wq, qb);
    score_kernel<<<dim3(1600), dim3(256), 0, stream>>>(x, pe, dbg, dbb, wq, qb, attnw, attnb, aoc, se);
    tcn_mfma_kernel<<<dim3(256), dim3(512), 0, stream>>>(x, wb, tcnb, tcng, tcnbb, out, se);
    gate_kernel<<<dim3(64), dim3(64), 0, stream>>>(se, fc1w, fc1b, fc2w, fc2b, gate);
    final_kernel<<<dim3(6400), dim3(256), 0, stream>>>(out, aoc, gate, bng, bnb);
}